// Round 15
// baseline (24.744 us; speedup 1.0000x reference)
//
#include <hip/hip_runtime.h>
#include <hip/hip_bf16.h>

#define B_   16
#define NC_  1024
#define NQ_  128
#define D_   512
#define NKT  4        // K-tiles: 512/128

typedef __attribute__((ext_vector_type(8))) short bf16x8;
typedef __attribute__((ext_vector_type(4))) float f32x4;

// fp32 -> bf16 RTNE
__device__ __forceinline__ short f2bf(float x) {
    return __builtin_bit_cast(short, __float2bfloat16(x));
}
// bf16 -> fp32 (exact)
__device__ __forceinline__ float bf2f(short s) {
    unsigned u = ((unsigned)(unsigned short)s) << 16;
    return __builtin_bit_cast(float, u);
}

// R15: fused kernel, BK=128 (4 rounds), side terms via VALU side-sums (R13-verified
// machinery — R14's side-term-MFMA failed because the w_cq fold on B poisoned qt).
//  A = bf16(c); B = bf16(q * w_cq); out = (A.B) + ct_i + qt_j + bias;
//  ct_i = sum c[i,:]*w_c, qt_j = sum q[j,:]*w_q — fp32 sums from RAW staged regs.
// Geometry: 64x64 tile, 4 waves 2Mx2N (wave 32x32), grid 512 (2 blocks/CU).
// LDS: 2 x (A bf16[64][128] 16KB | B bf16[64][128] 16KB) + weights 3KB + ct/qt 0.5KB.
// Pipeline: ISSUE(kt+1) top, COMPUTE(kt), WRITE(kt+1), lgkmcnt(0)+raw s_barrier
// (global loads never vmcnt-drained in the loop). Full unroll -> static indices.
// Swizzle: 16B chunk byte ^= ((row&7)<<4) within 256B rows (write+read).
__global__ __launch_bounds__(256, 2) void sim_kernel(
    const float* __restrict__ c, const float* __restrict__ q,
    const float* __restrict__ kern, const float* __restrict__ bias_p,
    float* __restrict__ out)
{
    __shared__ __align__(16) char  lds[2][32768];  // per buf: A@0 16KB | B@16384 16KB
    __shared__ __align__(16) short wcb[512];       // bf16 w_c
    __shared__ __align__(16) short wqb[512];       // bf16 w_q
    __shared__ __align__(16) short wcqb[512];      // bf16 w_cq
    __shared__ __align__(16) float ctl[64];
    __shared__ __align__(16) float qtl[64];

    const int bid   = blockIdx.x;
    const int b     = ((bid & 7) << 1) | (bid >> 8);   // XCD-affine batch (bijective)
    const int inner = (bid >> 3) & 31;
    const int mt    = inner >> 1;                      // 16 M-tiles of 64 rows
    const int nb    = inner & 1;                       // 2 N-halves of 64 cols
    const int tid   = threadIdx.x;
    const int lane  = tid & 63;
    const int w     = tid >> 6;
    const int wm    = w >> 1, wn = w & 1;              // 2x2 wave grid
    const int rif   = lane & 15;
    const int kg    = lane >> 4;

    // ---- weights -> LDS bf16 (once; 192 threads x 8 f32) ----
    if (tid < 192) {
        const float* s = kern + tid * 8;
        f32x4 v0 = *(const f32x4*)s;
        f32x4 v1 = *(const f32x4*)(s + 4);
        bf16x8 o;
        o[0]=f2bf(v0[0]); o[1]=f2bf(v0[1]); o[2]=f2bf(v0[2]); o[3]=f2bf(v0[3]);
        o[4]=f2bf(v1[0]); o[5]=f2bf(v1[1]); o[6]=f2bf(v1[2]); o[7]=f2bf(v1[3]);
        short* dst = (tid < 64) ? &wcb[tid * 8]
                   : (tid < 128) ? &wqb[(tid - 64) * 8]
                                 : &wcqb[(tid - 128) * 8];
        *(bf16x8*)dst = o;
    }

    // ---- staging geometry: thread -> row srow=tid>>2 (0..63), col slice (tid&3)*32 floats ----
    const int srow = tid >> 2;
    const int scol = (tid & 3) * 32;                   // float offset within 128-k window
    const float* ag = c + (size_t)(b * NC_ + mt * 64 + srow) * D_ + scol;
    const float* bg = q + (size_t)(b * NQ_ + nb * 64 + srow) * D_ + scol;
    int awc[4], bwc[4];
    #pragma unroll
    for (int i = 0; i < 4; ++i) {
        const int off = ((tid & 3) * 64 + i * 16) ^ ((srow & 7) << 4);
        awc[i] = srow * 256 + off;
        bwc[i] = 16384 + srow * 256 + off;
    }

    f32x4 sa[8], sb[8];                // one K-tile in flight per side (64 VGPR)
    float cta = 0.f, qta = 0.f;        // side sums from RAW fp32 staged values
    f32x4 acc00 = {}, acc01 = {}, acc10 = {}, acc11 = {};

#define ISSUE(T)                                                   \
    do { _Pragma("unroll")                                         \
        for (int i = 0; i < 8; ++i) {                              \
            sa[i] = *(const f32x4*)(ag + (T) * 128 + i * 4);       \
            sb[i] = *(const f32x4*)(bg + (T) * 128 + i * 4);       \
        }                                                          \
    } while (0)

#define WRITE(T)                                                               \
    do { char* Lw = &lds[(T) & 1][0];                                          \
        _Pragma("unroll")                                                      \
        for (int g = 0; g < 4; ++g) {                                          \
            bf16x8 wf  = *(const bf16x8*)&wcqb[(T) * 128 + scol + g * 8];      \
            bf16x8 wc8 = *(const bf16x8*)&wcb [(T) * 128 + scol + g * 8];      \
            bf16x8 wq8 = *(const bf16x8*)&wqb [(T) * 128 + scol + g * 8];      \
            bf16x8 oa, ob;                                                     \
            _Pragma("unroll")                                                  \
            for (int e = 0; e < 8; ++e) {                                      \
                float x = sa[g * 2 + (e >> 2)][e & 3];                         \
                float y = sb[g * 2 + (e >> 2)][e & 3];                         \
                oa[e] = f2bf(x);                                               \
                ob[e] = f2bf(y * bf2f(wf[e]));                                 \
                cta += x * bf2f(wc8[e]);                                       \
                qta += y * bf2f(wq8[e]);                                       \
            }                                                                  \
            *(bf16x8*)(Lw + awc[g]) = oa;                                      \
            *(bf16x8*)(Lw + bwc[g]) = ob;                                      \
        }                                                                      \
    } while (0)

#define COMPUTE(T)                                                                                   \
    do { const char* L = &lds[(T) & 1][0];                                                           \
        _Pragma("unroll")                                                                            \
        for (int kk = 0; kk < 4; ++kk) {                                                             \
            const int ksb = kk * 64 + kg * 16;                                                       \
            bf16x8 af0, af1, bf0, bf1;                                                               \
            { int r = wm*32 + rif;      af0 = *(const bf16x8*)(L + r*256 + (ksb ^ ((r & 7) << 4))); } \
            { int r = wm*32 + 16 + rif; af1 = *(const bf16x8*)(L + r*256 + (ksb ^ ((r & 7) << 4))); } \
            { int j = wn*32 + rif;      bf0 = *(const bf16x8*)(L + 16384 + j*256 + (ksb ^ ((j & 7) << 4))); } \
            { int j = wn*32 + 16 + rif; bf1 = *(const bf16x8*)(L + 16384 + j*256 + (ksb ^ ((j & 7) << 4))); } \
            acc00 = __builtin_amdgcn_mfma_f32_16x16x32_bf16(af0, bf0, acc00, 0, 0, 0);               \
            acc01 = __builtin_amdgcn_mfma_f32_16x16x32_bf16(af0, bf1, acc01, 0, 0, 0);               \
            acc10 = __builtin_amdgcn_mfma_f32_16x16x32_bf16(af1, bf0, acc10, 0, 0, 0);               \
            acc11 = __builtin_amdgcn_mfma_f32_16x16x32_bf16(af1, bf1, acc11, 0, 0, 0);               \
        }                                                                                            \
    } while (0)

    // ---- prologue ----
    ISSUE(0);
    asm volatile("s_waitcnt lgkmcnt(0)" ::: "memory");   // weight ds_writes drained
    __builtin_amdgcn_sched_barrier(0);
    __builtin_amdgcn_s_barrier();                        // weights visible
    WRITE(0);                                            // waits tile0 vmcnt internally
    asm volatile("s_waitcnt lgkmcnt(0)" ::: "memory");
    __builtin_amdgcn_sched_barrier(0);
    __builtin_amdgcn_s_barrier();                        // buf0 ready

    #pragma unroll
    for (int kt = 0; kt < NKT; ++kt) {
        if (kt + 1 < NKT) ISSUE(kt + 1);                 // issue next tile's globals early
        __builtin_amdgcn_sched_barrier(0);               // pin issue above compute
        COMPUTE(kt);
        if (kt + 1 < NKT) {
            WRITE(kt + 1);                               // consume regs, write other buf
            asm volatile("s_waitcnt lgkmcnt(0)" ::: "memory");
            __builtin_amdgcn_sched_barrier(0);
            __builtin_amdgcn_s_barrier();
        }
    }
#undef ISSUE
#undef WRITE
#undef COMPUTE

    // ---- side-term reductions: 4 threads (tid&3) share row srow for both A and B ----
    cta += __shfl_xor(cta, 1); cta += __shfl_xor(cta, 2);
    qta += __shfl_xor(qta, 1); qta += __shfl_xor(qta, 2);
    if ((tid & 3) == 0) { ctl[srow] = cta; qtl[srow] = qta; }
    asm volatile("s_waitcnt lgkmcnt(0)" ::: "memory");
    __builtin_amdgcn_sched_barrier(0);
    __builtin_amdgcn_s_barrier();

    // ---- epilogue: out = cq + ct + qt + bias ----
    const float bias = *bias_p;
    const float q0 = qtl[wn * 32 + rif]      + bias;
    const float q1 = qtl[wn * 32 + 16 + rif] + bias;
    #pragma unroll
    for (int mf = 0; mf < 2; ++mf) {
        const f32x4 a0 = mf ? acc10 : acc00;
        const f32x4 a1 = mf ? acc11 : acc01;
        const f32x4 cv = *(const f32x4*)&ctl[wm * 32 + mf * 16 + kg * 4];
        float* o = out + ((size_t)(b * NC_ + mt * 64 + wm * 32 + mf * 16 + kg * 4)) * NQ_
                 + nb * 64 + wn * 32 + rif;
        #pragma unroll
        for (int r = 0; r < 4; ++r) {
            o[(size_t)r * NQ_ +  0] = a0[r] + cv[r] + q0;
            o[(size_t)r * NQ_ + 16] = a1[r] + cv[r] + q1;
        }
    }
}

extern "C" void kernel_launch(void* const* d_in, const int* in_sizes, int n_in,
                              void* d_out, int out_size, void* d_ws, size_t ws_size,
                              hipStream_t stream) {
    const float* c    = (const float*)d_in[0];
    const float* q    = (const float*)d_in[1];
    const float* kern = (const float*)d_in[2];
    const float* bias = (const float*)d_in[3];
    float* out = (float*)d_out;

    // Single fused launch: 16 b x 16 mt x 2 nb = 512 blocks (XCD-affine decode in-kernel).
    sim_kernel<<<512, 256, 0, stream>>>(c, q, kern, bias, out);
}

// Round 16
// 19.135 us; speedup vs baseline: 1.2931x; 1.2931x over previous
//
#include <hip/hip_runtime.h>
#include <hip/hip_bf16.h>

#define B_   16
#define NC_  1024
#define NQ_  128
#define D_   512
#define NKT  8        // K-tiles: 512/64

typedef __attribute__((ext_vector_type(8))) short bf16x8;
typedef __attribute__((ext_vector_type(4))) float f32x4;

// fp32 -> bf16 RTNE
__device__ __forceinline__ short f2bf(float x) {
    return __builtin_bit_cast(short, __float2bfloat16(x));
}
// bf16 -> fp32 (exact)
__device__ __forceinline__ float bf2f(short s) {
    unsigned u = ((unsigned)(unsigned short)s) << 16;
    return __builtin_bit_cast(float, u);
}

// R16: R13's verified pipeline (BK=64, ring-2, ISSUE(kt+2) 2-deep lookahead,
// raw s_barrier + lgkmcnt(0) only), ONE change: BM 64->32 => grid 1024 =
// 4 blocks/CU (R13 was grid-limited to 2). Wave tile 16x32 (2Mx2N).
//  A = bf16(c); B = bf16(q*w_cq); ct,qt = fp32 side-sums in WRITE from raw regs.
// LDS: 2 x (A bf16[32][64] 4KB | B bf16[64][64] 8KB) + weights 3KB + ct/qt.
// Swizzle: 16B chunk, byte ^= ((row&7)<<4) within 128B rows (write+read).
__global__ __launch_bounds__(256, 4) void sim_kernel(
    const float* __restrict__ c, const float* __restrict__ q,
    const float* __restrict__ kern, const float* __restrict__ bias_p,
    float* __restrict__ out)
{
    __shared__ __align__(16) char  lds[2][12288];  // per buf: A@0 4KB | B@4096 8KB
    __shared__ __align__(16) short wcb[512];       // bf16 w_c
    __shared__ __align__(16) short wqb[512];       // bf16 w_q
    __shared__ __align__(16) short wcqb[512];      // bf16 w_cq
    __shared__ __align__(16) float ctl[32];
    __shared__ __align__(16) float qtl[64];

    const int bid   = blockIdx.x;
    const int b     = ((bid & 7) << 1) | (bid >> 9);   // XCD-affine batch (bijective, 1024 blocks)
    const int inner = (bid >> 3) & 63;
    const int mt    = inner >> 1;                      // 32 M-tiles of 32 rows
    const int nb    = inner & 1;                       // 2 N-halves of 64 cols
    const int tid   = threadIdx.x;
    const int lane  = tid & 63;
    const int w     = tid >> 6;
    const int wm    = w >> 1, wn = w & 1;              // 2x2 wave grid; wave tile 16x32
    const int rif   = lane & 15;
    const int kg    = lane >> 4;

    // ---- weights -> LDS bf16 (once; 192 threads x 8 f32) ----
    if (tid < 192) {
        const float* s = kern + tid * 8;
        f32x4 v0 = *(const f32x4*)s;
        f32x4 v1 = *(const f32x4*)(s + 4);
        bf16x8 o;
        o[0]=f2bf(v0[0]); o[1]=f2bf(v0[1]); o[2]=f2bf(v0[2]); o[3]=f2bf(v0[3]);
        o[4]=f2bf(v1[0]); o[5]=f2bf(v1[1]); o[6]=f2bf(v1[2]); o[7]=f2bf(v1[3]);
        short* dst = (tid < 64) ? &wcb[tid * 8]
                   : (tid < 128) ? &wqb[(tid - 64) * 8]
                                 : &wcqb[(tid - 128) * 8];
        *(bf16x8*)dst = o;
    }

    // ---- A staging: thread -> row ar=tid>>3 (0..31), col slice (tid&7)*8 floats ----
    const int ar  = tid >> 3;
    const int acs = (tid & 7) * 8;
    const float* ag = c + (size_t)(b * NC_ + mt * 32 + ar) * D_ + acs;
    const int awc = ar * 128 + ((acs * 2) ^ ((ar & 7) << 4));

    // ---- B staging: thread -> row br=tid>>2 (0..63), col slice (tid&3)*16 floats ----
    const int br  = tid >> 2;
    const int bcs = (tid & 3) * 16;
    const float* bg = q + (size_t)(b * NQ_ + nb * 64 + br) * D_ + bcs;
    const int bwc0 = 4096 + br * 128 + ((bcs * 2)      ^ ((br & 7) << 4));
    const int bwc1 = 4096 + br * 128 + ((bcs * 2 + 16) ^ ((br & 7) << 4));

    f32x4 sa[2][2], sb[2][4];          // 2 tiles in flight (static idx after unroll)
    float cta = 0.f, qta = 0.f;        // side sums from RAW fp32 staged values
    f32x4 acc0 = {}, acc1 = {};

#define ISSUE(T)                                                   \
    do { const int s_ = (T) & 1;                                   \
        sa[s_][0] = *(const f32x4*)(ag + (T) * 64);                \
        sa[s_][1] = *(const f32x4*)(ag + (T) * 64 + 4);            \
        sb[s_][0] = *(const f32x4*)(bg + (T) * 64);                \
        sb[s_][1] = *(const f32x4*)(bg + (T) * 64 + 4);            \
        sb[s_][2] = *(const f32x4*)(bg + (T) * 64 + 8);            \
        sb[s_][3] = *(const f32x4*)(bg + (T) * 64 + 12);           \
    } while (0)

#define WRITE(T)                                                               \
    do { const int s_ = (T) & 1; char* Lw = &lds[s_][0];                       \
        bf16x8 wc8 = *(const bf16x8*)&wcb [(T) * 64 + acs];                    \
        bf16x8 oa;                                                             \
        _Pragma("unroll")                                                      \
        for (int e = 0; e < 8; ++e) {                                          \
            float x = sa[s_][e >> 2][e & 3];                                   \
            oa[e] = f2bf(x);                                                   \
            cta += x * bf2f(wc8[e]);                                           \
        }                                                                      \
        *(bf16x8*)(Lw + awc) = oa;                                             \
        bf16x8 wf0 = *(const bf16x8*)&wcqb[(T) * 64 + bcs];                    \
        bf16x8 wf1 = *(const bf16x8*)&wcqb[(T) * 64 + bcs + 8];                \
        bf16x8 wq0 = *(const bf16x8*)&wqb [(T) * 64 + bcs];                    \
        bf16x8 wq1 = *(const bf16x8*)&wqb [(T) * 64 + bcs + 8];                \
        bf16x8 ob0, ob1;                                                       \
        _Pragma("unroll")                                                      \
        for (int e = 0; e < 8; ++e) {                                          \
            float y0 = sb[s_][e >> 2][e & 3];                                  \
            float y1 = sb[s_][2 + (e >> 2)][e & 3];                            \
            ob0[e] = f2bf(y0 * bf2f(wf0[e]));                                  \
            ob1[e] = f2bf(y1 * bf2f(wf1[e]));                                  \
            qta += y0 * bf2f(wq0[e]) + y1 * bf2f(wq1[e]);                      \
        }                                                                      \
        *(bf16x8*)(Lw + bwc0) = ob0;                                           \
        *(bf16x8*)(Lw + bwc1) = ob1;                                           \
    } while (0)

#define COMPUTE(T)                                                                                   \
    do { const char* L = &lds[(T) & 1][0];                                                           \
        _Pragma("unroll")                                                                            \
        for (int kk = 0; kk < 2; ++kk) {                                                             \
            const int ks = kk * 64 + kg * 16;                                                        \
            bf16x8 af0, bf0, bf1;                                                                    \
            { int r = wm*16 + rif;      af0 = *(const bf16x8*)(L + r*128 + (ks ^ ((r & 7) << 4))); } \
            { int j = wn*32 + rif;      bf0 = *(const bf16x8*)(L + 4096 + j*128 + (ks ^ ((j & 7) << 4))); } \
            { int j = wn*32 + 16 + rif; bf1 = *(const bf16x8*)(L + 4096 + j*128 + (ks ^ ((j & 7) << 4))); } \
            acc0 = __builtin_amdgcn_mfma_f32_16x16x32_bf16(af0, bf0, acc0, 0, 0, 0);                 \
            acc1 = __builtin_amdgcn_mfma_f32_16x16x32_bf16(af0, bf1, acc1, 0, 0, 0);                 \
        }                                                                                            \
    } while (0)

    // ---- prologue ----
    ISSUE(0); ISSUE(1);
    asm volatile("s_waitcnt lgkmcnt(0)" ::: "memory");   // weight ds_writes drained
    __builtin_amdgcn_sched_barrier(0);
    __builtin_amdgcn_s_barrier();                        // weights visible
    WRITE(0);                                            // waits tile0 vmcnt internally
    asm volatile("s_waitcnt lgkmcnt(0)" ::: "memory");
    __builtin_amdgcn_sched_barrier(0);
    __builtin_amdgcn_s_barrier();                        // buf0 ready

    #pragma unroll
    for (int kt = 0; kt < NKT; ++kt) {
        if (kt + 2 < NKT) ISSUE(kt + 2);                 // 2-deep lookahead (R13-verified)
        __builtin_amdgcn_sched_barrier(0);               // pin issue above compute
        COMPUTE(kt);
        if (kt + 1 < NKT) {
            WRITE(kt + 1);                               // consumes regs issued at kt-1
            asm volatile("s_waitcnt lgkmcnt(0)" ::: "memory");
            __builtin_amdgcn_sched_barrier(0);
            __builtin_amdgcn_s_barrier();
        }
    }
#undef ISSUE
#undef WRITE
#undef COMPUTE

    // ---- side-term reductions ----
    cta += __shfl_xor(cta, 1); cta += __shfl_xor(cta, 2); cta += __shfl_xor(cta, 4);
    qta += __shfl_xor(qta, 1); qta += __shfl_xor(qta, 2);
    if ((tid & 7) == 0) ctl[ar] = cta;
    if ((tid & 3) == 0) qtl[br] = qta;
    asm volatile("s_waitcnt lgkmcnt(0)" ::: "memory");
    __builtin_amdgcn_sched_barrier(0);
    __builtin_amdgcn_s_barrier();

    // ---- epilogue: out = cq + ct + qt + bias ----
    const float bias = *bias_p;
    const float q0 = qtl[wn * 32 + rif]      + bias;
    const float q1 = qtl[wn * 32 + 16 + rif] + bias;
    const f32x4 cv = *(const f32x4*)&ctl[wm * 16 + kg * 4];
    float* o = out + ((size_t)(b * NC_ + mt * 32 + wm * 16 + kg * 4)) * NQ_
             + nb * 64 + wn * 32 + rif;
    #pragma unroll
    for (int r = 0; r < 4; ++r) {
        o[(size_t)r * NQ_ +  0] = acc0[r] + cv[r] + q0;
        o[(size_t)r * NQ_ + 16] = acc1[r] + cv[r] + q1;
    }
}

extern "C" void kernel_launch(void* const* d_in, const int* in_sizes, int n_in,
                              void* d_out, int out_size, void* d_ws, size_t ws_size,
                              hipStream_t stream) {
    const float* c    = (const float*)d_in[0];
    const float* q    = (const float*)d_in[1];
    const float* kern = (const float*)d_in[2];
    const float* bias = (const float*)d_in[3];
    float* out = (float*)d_out;

    // Single fused launch: 16 b x 32 mt x 2 nb = 1024 blocks (XCD-affine decode in-kernel).
    sim_kernel<<<1024, 256, 0, stream>>>(c, q, kern, bias, out);
}